// Round 4
// baseline (315.991 us; speedup 1.0000x reference)
//
#include <hip/hip_runtime.h>
#include <hip/hip_bf16.h>

// LocalBlock: fused tpose+LN1 -> qkv GEMM -> multi-dilate local attn(+xn) -> proj GEMM(+x)
//            -> LN2 -> fc1+gelu -> fc2(+x, transposed out)
// B=8 C=384 H=W=56 N=25088 NH=12 hd=32 dils=(1,2,3) HID=1536

#define B_   8
#define C_   384
#define W_   56
#define HW_  3136
#define N_   25088
#define HD_  32
#define HID_ 1536
#define C3_  1152

typedef __attribute__((ext_vector_type(8))) short short8v;
typedef __attribute__((ext_vector_type(4))) float f32x4;
typedef __attribute__((ext_vector_type(4))) unsigned short ushort4v;

__device__ __forceinline__ float bf2f(unsigned short u) {
  union { float f; unsigned u; } c; c.u = ((unsigned)u) << 16; return c.f;
}
__device__ __forceinline__ unsigned short f2bf(float f) {
  unsigned u = __float_as_uint(f);
  u = (u + 0x7FFFu + ((u >> 16) & 1u)) >> 16;
  return (unsigned short)u;
}

#define GLL(gsrc, ldst) __builtin_amdgcn_global_load_lds( \
    (const __attribute__((address_space(1))) void*)(gsrc), \
    (__attribute__((address_space(3))) void*)(ldst), 16, 0, 0)

// ---------------- weight fp32 -> bf16 MFMA bricks ----------------
// brick: 16 n-cols x 32 k: 1KB, lane-linear: lane = (n&15) + (((k>>3)&3)<<4), elem = k&7
// addr(ushort) = ((n>>4)*(K>>5) + (k>>5))*512 + lane*8 + elem
__device__ __forceinline__ void brick_one(const float* src, unsigned short* dst,
                                          int idx, int K) {
  const int n = idx / K, k = idx - n * K;
  const int lane = (n & 15) + (((k >> 3) & 3) << 4);
  dst[(size_t)((n >> 4) * (K >> 5) + (k >> 5)) * 512 + lane * 8 + (k & 7)] = f2bf(src[idx]);
}
__global__ void repack_w(const float* __restrict__ qw, const float* __restrict__ pw,
                         const float* __restrict__ f1, const float* __restrict__ f2,
                         unsigned short* __restrict__ o) {
  int i = blockIdx.x * 256 + threadIdx.x;
  if (i < 442368)        brick_one(qw, o, i, 384);
  else if (i < 589824)   brick_one(pw, o + 442368, i - 442368, 384);
  else if (i < 1179648)  brick_one(f1, o + 589824, i - 589824, 384);
  else if (i < 1769472)  brick_one(f2, o + 1179648, i - 1179648, 1536);
}

// ---------------- fused transpose + LN1: x[B,C,HW] -> xp[N,C] f32, xn[N,C] bf16 ----------------
__global__ __launch_bounds__(256)
void tpose_ln(const float* __restrict__ x, float* __restrict__ xp,
              unsigned short* __restrict__ xnb,
              const float* __restrict__ gam, const float* __restrict__ bet) {
  __shared__ float ft[64][385];
  __shared__ float mstat[64], rstat[64];
  const int tid = threadIdx.x;
  const int nb0 = blockIdx.x * 64;
  const int bb = nb0 / HW_, hw0 = nb0 - bb * HW_;
  const float* xb = x + (size_t)bb * C_ * HW_ + hw0;
#pragma unroll
  for (int p = 0; p < 24; ++p) {
    const int c = p * 16 + (tid >> 4);
    f32x4 v = *(const f32x4*)&xb[(size_t)c * HW_ + (tid & 15) * 4];
#pragma unroll
    for (int j = 0; j < 4; ++j) ft[(tid & 15) * 4 + j][c] = v[j];
  }
  __syncthreads();
  const int l16 = tid & 15, g16 = tid >> 4;
#pragma unroll
  for (int rr = 0; rr < 4; ++rr) {
    const int row = g16 * 4 + rr;
    float s = 0.f, ss = 0.f;
#pragma unroll
    for (int k2 = 0; k2 < 24; ++k2) { float v = ft[row][l16 + k2 * 16]; s += v; ss += v * v; }
    s += __shfl_xor(s, 8); ss += __shfl_xor(ss, 8);
    s += __shfl_xor(s, 4); ss += __shfl_xor(ss, 4);
    s += __shfl_xor(s, 2); ss += __shfl_xor(ss, 2);
    s += __shfl_xor(s, 1); ss += __shfl_xor(ss, 1);
    if (l16 == 0) {
      const float mean = s * (1.f / 384.f);
      const float var = ss * (1.f / 384.f) - mean * mean;
      mstat[row] = mean; rstat[row] = rsqrtf(var + 1e-5f);
    }
  }
  __syncthreads();
  const int row = tid >> 2, part = tid & 3;
  const float mean = mstat[row], rstd = rstat[row];
  float* xpr = xp + (size_t)(nb0 + row) * C_ + part * 96;
  unsigned short* xr = xnb + (size_t)(nb0 + row) * C_ + part * 96;
#pragma unroll
  for (int q = 0; q < 12; ++q) {
    short8v o;
    f32x4 v0, v1;
#pragma unroll
    for (int e = 0; e < 8; ++e) {
      const int c = part * 96 + q * 8 + e;
      const float v = ft[row][c];
      if (e < 4) v0[e] = v; else v1[e - 4] = v;
      o[e] = (short)f2bf((v - mean) * rstd * gam[c] + bet[c]);
    }
    *(f32x4*)&xpr[q * 8] = v0;
    *(f32x4*)&xpr[q * 8 + 4] = v1;
    *(short8v*)&xr[q * 8] = o;
  }
}

// ---------------- row LayerNorm (fp32 in) -> bf16 out (LN2) ----------------
__global__ __launch_bounds__(256)
void ln_rows(const float* __restrict__ in, unsigned short* __restrict__ outb,
             const float* __restrict__ g, const float* __restrict__ bb) {
  const int row = blockIdx.x * 4 + (threadIdx.x >> 6);
  const int lane = threadIdx.x & 63;
  const float* rp = in + (size_t)row * C_;
  float v[6]; float s = 0.f, ss = 0.f;
#pragma unroll
  for (int j = 0; j < 6; ++j) { v[j] = rp[lane + j * 64]; s += v[j]; ss += v[j] * v[j]; }
#pragma unroll
  for (int off = 32; off; off >>= 1) { s += __shfl_xor(s, off); ss += __shfl_xor(ss, off); }
  const float mean = s * (1.f / 384.f);
  const float var = ss * (1.f / 384.f) - mean * mean;
  const float rstd = rsqrtf(var + 1e-5f);
  unsigned short* op = outb + (size_t)row * C_;
#pragma unroll
  for (int j = 0; j < 6; ++j) {
    const int c = lane + j * 64;
    op[c] = f2bf((v[j] - mean) * rstd * g[c] + bb[c]);
  }
}

// ---------------- MFMA GEMM: out[M,Nn] = A[M,K](bf16,row-major) @ W[Nn,K]^T(bricked) --------
// 256 thr / 4 waves (2M x 2N), block tile 128x128, wave tile 64x64, BK=64.
// A: LDS ring-3 x 16KB (XOR-swizzled via pre-swizzled GLL source), staged 2 sub-iters ahead,
//    counted vmcnt(20/8), one raw barrier per sub-iter.
// B: registers, loaded from weight bricks (L2-resident, compiler-managed waits), 2 ahead.
// MODE 0: bf16 out (qkv, no bias), SWAPPED mfma, LDS-transposed coalesced stores
// MODE 1: f32 out = resid + v + bias (proj, in-place), direct stores
// MODE 2: bf16 out = gelu(v + bias) (fc1), SWAPPED, LDS-transposed stores
// MODE 3: f32 d_out[B,C,HW] = resid + v + bias, LDS-transposed stores
template <int MODE>
__global__ __launch_bounds__(256, 2)
void gemmK(const unsigned short* __restrict__ A, const unsigned short* __restrict__ Wb,
           const float* __restrict__ bias, const float* __restrict__ resid,
           void* __restrict__ outp, int Nout, int K) {
  constexpr bool SWAP = (MODE == 0 || MODE == 2);
  __shared__ unsigned short sm[24576];   // 48 KiB: 3 x [128][64] bf16 A-slots
  const int tid = threadIdx.x;
  const int l = tid & 63, wv = tid >> 6;
  const int wm = wv >> 1, wn = wv & 1;
  const int m0 = blockIdx.y * 128, n0 = blockIdx.x * 128;
  const int KB = K >> 5;

  // ---- A staging (pre-swizzled source cols; LDS linear) ----
  const unsigned short* gA = A + (size_t)(m0 + (tid >> 3)) * K
                               + (((tid & 7) ^ ((tid >> 3) & 7)) << 3);
  const int dst0 = tid << 3;
  auto stage = [&](int kt, int so) {
#pragma unroll
    for (int r = 0; r < 4; ++r)
      GLL(gA + (size_t)kt * 64 + (size_t)r * 32 * K, &sm[so + r * 2048 + dst0]);
  };

  // ---- B bricks -> registers ----
  const unsigned short* wbW = Wb + (size_t)((n0 >> 4) + wn * 4) * KB * 512 + (l << 3);
  short8v b0[8], b1[8];
  auto loadB = [&](short8v* dst, int kt) {
#pragma unroll
    for (int nt = 0; nt < 4; ++nt) {
      const unsigned short* p = wbW + (size_t)(nt * KB + kt * 2) * 512;
      dst[nt] = *(const short8v*)p;
      dst[4 + nt] = *(const short8v*)(p + 512);
    }
  };

  const int fr = l & 15, g = l >> 4, g4 = (l >> 4) << 2;
  int ar[4];
#pragma unroll
  for (int mt = 0; mt < 4; ++mt) ar[mt] = (wm * 64 + mt * 16 + fr) * 64;
  const int sl0 = (g ^ (fr & 7)) << 3;
  const int sl1 = ((4 + g) ^ (fr & 7)) << 3;

  f32x4 acc[4][4] = {};
  const int KT = K >> 6;   // 6 (K=384) or 24 (K=1536), always even

  auto phase = [&](int so, int sl, const short8v* bh) {
    short8v av[4];
#pragma unroll
    for (int mt = 0; mt < 4; ++mt) av[mt] = *(const short8v*)&sm[so + ar[mt] + sl];
    asm volatile("s_waitcnt lgkmcnt(0)" ::: "memory");
    __builtin_amdgcn_sched_barrier(0);
    __builtin_amdgcn_s_setprio(1);
#pragma unroll
    for (int mt = 0; mt < 4; ++mt)
#pragma unroll
      for (int nt = 0; nt < 4; ++nt)
        acc[mt][nt] = SWAP
          ? __builtin_amdgcn_mfma_f32_16x16x32_bf16(bh[nt], av[mt], acc[mt][nt], 0, 0, 0)
          : __builtin_amdgcn_mfma_f32_16x16x32_bf16(av[mt], bh[nt], acc[mt][nt], 0, 0, 0);
    __builtin_amdgcn_s_setprio(0);
    __builtin_amdgcn_sched_barrier(0);
  };

  int oA = 0, oB = 8192, oC = 16384;
  stage(0, oA);  __builtin_amdgcn_sched_barrier(0);
  loadB(b0, 0);  __builtin_amdgcn_sched_barrier(0);
  stage(1, oB);  __builtin_amdgcn_sched_barrier(0);
  loadB(b1, 1);  __builtin_amdgcn_sched_barrier(0);

  for (int kt = 0; kt < KT; kt += 2) {
    // -------- even sub-iter: slot oA, regs b0 --------
    asm volatile("s_waitcnt vmcnt(20)" ::: "memory");
    __builtin_amdgcn_sched_barrier(0);
    __builtin_amdgcn_s_barrier();
    __builtin_amdgcn_sched_barrier(0);
    if (kt + 2 < KT) stage(kt + 2, oC);
    __builtin_amdgcn_sched_barrier(0);
    phase(oA, sl0, &b0[0]);
    phase(oA, sl1, &b0[4]);
    if (kt + 2 < KT) loadB(b0, kt + 2);
    __builtin_amdgcn_sched_barrier(0);
    // -------- odd sub-iter: slot oB, regs b1 --------
    if (kt + 3 < KT) asm volatile("s_waitcnt vmcnt(20)" ::: "memory");
    else             asm volatile("s_waitcnt vmcnt(8)" ::: "memory");
    __builtin_amdgcn_sched_barrier(0);
    __builtin_amdgcn_s_barrier();
    __builtin_amdgcn_sched_barrier(0);
    if (kt + 3 < KT) stage(kt + 3, oA);
    __builtin_amdgcn_sched_barrier(0);
    phase(oB, sl0, &b1[0]);
    phase(oB, sl1, &b1[4]);
    if (kt + 3 < KT) loadB(b1, kt + 3);
    __builtin_amdgcn_sched_barrier(0);
    // rotate ring: (oA,oB,oC) <- (oC, old oA, oB)
    int t = oA; oA = oC; oC = oB; oB = t;
  }

  __syncthreads();   // K-loop LDS reads done everywhere; reuse sm for epilogue

  if (SWAP) {
    // lane holds: m = wm*64+mt*16+fr ; n = wn*64+nt*16+g4+j (j = acc elem)
    unsigned short* eb = sm;  // [128 m][128 n] bf16, 16B-group swizzled by (m&7)
#pragma unroll
    for (int mt = 0; mt < 4; ++mt) {
      const int ml = wm * 64 + mt * 16 + fr;
#pragma unroll
      for (int nt = 0; nt < 4; ++nt) {
        const int nlb = wn * 64 + nt * 16 + g4;
        f32x4 v = acc[mt][nt];
        ushort4v pk;
        if (MODE == 2) {
          const f32x4 b4 = *(const f32x4*)&bias[n0 + nlb];
#pragma unroll
          for (int j = 0; j < 4; ++j) {
            const float xv = v[j] + b4[j];
            pk[j] = f2bf(0.5f * xv * (1.f + erff(xv * 0.70710678118f)));
          }
        } else {
#pragma unroll
          for (int j = 0; j < 4; ++j) pk[j] = f2bf(v[j]);
        }
        const int sg = (nlb >> 3) ^ (ml & 7);
        *(ushort4v*)&eb[ml * 128 + sg * 8 + (nlb & 7)] = pk;
      }
    }
    __syncthreads();
    unsigned short* op = (unsigned short*)outp;
#pragma unroll
    for (int i = 0; i < 8; ++i) {
      const int idx = i * 256 + tid;
      const int row = idx >> 4, ch = idx & 15;
      short8v v = *(const short8v*)&sm[row * 128 + ((ch ^ (row & 7)) << 3)];
      *(short8v*)&op[(size_t)(m0 + row) * Nout + n0 + ch * 8] = v;
    }
  } else if (MODE == 1) {
    // lane holds: m = wm*64+mt*16+g4+j ; n = wn*64+nt*16+fr
    float* out = (float*)outp;
#pragma unroll
    for (int mt = 0; mt < 4; ++mt) {
      const int mb = m0 + wm * 64 + mt * 16 + g4;
#pragma unroll
      for (int nt = 0; nt < 4; ++nt) {
        const int o = n0 + wn * 64 + nt * 16 + fr;
        const float bo = bias[o];
#pragma unroll
        for (int j = 0; j < 4; ++j) {
          const size_t ix = (size_t)(mb + j) * C_ + o;
          out[ix] = resid[ix] + acc[mt][nt][j] + bo;
        }
      }
    }
  } else {  // MODE 3: transposed f32 store to d_out[B,C,HW], two 64-col passes
    float* lf = (float*)sm;   // [64 c][128 rows] f32, row4 ^ (c&7) swizzle
    float* out = (float*)outp;
#pragma unroll
    for (int p = 0; p < 2; ++p) {
      if (wn == p) {
#pragma unroll
        for (int mt = 0; mt < 4; ++mt) {
          const int row4 = wm * 16 + mt * 4 + g;
#pragma unroll
          for (int nt = 0; nt < 4; ++nt) {
            const int c = nt * 16 + fr;
            const int o = n0 + p * 64 + c;
            const float bo = bias[o];
            f32x4 v = acc[mt][nt];
#pragma unroll
            for (int j = 0; j < 4; ++j)
              v[j] = v[j] + bo + resid[(size_t)(m0 + row4 * 4 + j) * C_ + o];
            *(f32x4*)&lf[c * 128 + ((row4 ^ (c & 7)) << 2)] = v;
          }
        }
      }
      __syncthreads();
      const int c2 = tid >> 2, q = tid & 3;
#pragma unroll
      for (int i = 0; i < 8; ++i) {
        const int row4r = q * 8 + i;
        f32x4 v = *(const f32x4*)&lf[c2 * 128 + ((row4r ^ (c2 & 7)) << 2)];
        const int col = n0 + p * 64 + c2;
        const int mg = m0 + row4r * 4;
        const int bb2 = mg / HW_;
        const int hw = mg - bb2 * HW_;
        *(f32x4*)&out[((size_t)bb2 * C_ + col) * HW_ + hw] = v;
      }
      __syncthreads();
    }
  }
}

// ---------------- multi-dilate local attention ----------------
__global__ __launch_bounds__(256)
void attn_kernel(const unsigned short* __restrict__ qkv,
                 const unsigned short* __restrict__ xn,
                 unsigned short* __restrict__ aout) {
  const int gid = blockIdx.x * 256 + threadIdx.x;
  const int n = gid / 12;
  const int r = gid - n * 12;
  const int dil = (r >> 2) + 1;
  const int b = n / HW_;
  const int hw = n - b * HW_;
  const int h = hw / W_;
  const int w = hw - h * W_;

  const size_t base = (size_t)n * C3_ + (size_t)r * HD_;
  float q[32];
  {
    const short8v* vp = (const short8v*)(qkv + base);
#pragma unroll
    for (int c8 = 0; c8 < 4; ++c8) {
      short8v v = vp[c8];
#pragma unroll
      for (int e = 0; e < 8; ++e) q[c8 * 8 + e] = bf2f((unsigned short)v[e]);
    }
  }

  float logit[9];
#pragma unroll
  for (int ti = 0; ti < 3; ++ti)
#pragma unroll
    for (int tj = 0; tj < 3; ++tj) {
      const int t = ti * 3 + tj;
      const int hn = h + (ti - 1) * dil, wn = w + (tj - 1) * dil;
      if ((unsigned)hn < 56u && (unsigned)wn < 56u) {
        const int nb = n + (ti - 1) * dil * W_ + (tj - 1) * dil;
        const short8v* kp = (const short8v*)(qkv + (size_t)nb * C3_ + C_ + (size_t)r * HD_);
        float dot = 0.f;
#pragma unroll
        for (int c8 = 0; c8 < 4; ++c8) {
          short8v v = kp[c8];
#pragma unroll
          for (int e = 0; e < 8; ++e) dot += q[c8 * 8 + e] * bf2f((unsigned short)v[e]);
        }
        logit[t] = dot * 0.17677669529663688f;  // 32^-0.5
      } else {
        logit[t] = 0.f;  // zero-padded taps participate with logit 0
      }
    }

  float mx = logit[0];
#pragma unroll
  for (int t = 1; t < 9; ++t) mx = fmaxf(mx, logit[t]);
  float wgt[9]; float se = 0.f;
#pragma unroll
  for (int t = 0; t < 9; ++t) { wgt[t] = __expf(logit[t] - mx); se += wgt[t]; }
  const float inv = 1.f / se;

  float acc[32];
#pragma unroll
  for (int c = 0; c < 32; ++c) acc[c] = 0.f;
#pragma unroll
  for (int ti = 0; ti < 3; ++ti)
#pragma unroll
    for (int tj = 0; tj < 3; ++tj) {
      const int t = ti * 3 + tj;
      const int hn = h + (ti - 1) * dil, wn = w + (tj - 1) * dil;
      if ((unsigned)hn < 56u && (unsigned)wn < 56u) {
        const int nb = n + (ti - 1) * dil * W_ + (tj - 1) * dil;
        const short8v* vp = (const short8v*)(qkv + (size_t)nb * C3_ + 2 * C_ + (size_t)r * HD_);
        const float wt = wgt[t];
#pragma unroll
        for (int c8 = 0; c8 < 4; ++c8) {
          short8v v = vp[c8];
#pragma unroll
          for (int e = 0; e < 8; ++e) acc[c8 * 8 + e] += wt * bf2f((unsigned short)v[e]);
        }
      }
    }

  const size_t obase = (size_t)n * C_ + (size_t)r * HD_;
  const short8v* xv = (const short8v*)(xn + obase);
  short8v ov[4];
#pragma unroll
  for (int c8 = 0; c8 < 4; ++c8) {
    short8v v = xv[c8];
#pragma unroll
    for (int e = 0; e < 8; ++e)
      ov[c8][e] = (short)f2bf(acc[c8 * 8 + e] * inv + bf2f((unsigned short)v[e]));
  }
  short8v* op = (short8v*)(aout + obase);
#pragma unroll
  for (int c8 = 0; c8 < 4; ++c8) op[c8] = ov[c8];
}

extern "C" void kernel_launch(void* const* d_in, const int* in_sizes, int n_in,
                              void* d_out, int out_size, void* d_ws, size_t ws_size,
                              hipStream_t stream) {
  const float* x = (const float*)d_in[0];
  const float* qkv_w = (const float*)d_in[1];
  const float* proj_w = (const float*)d_in[2];
  const float* proj_b = (const float*)d_in[3];
  const float* n1_g = (const float*)d_in[4];
  const float* n1_b = (const float*)d_in[5];
  const float* n2_g = (const float*)d_in[6];
  const float* n2_b = (const float*)d_in[7];
  const float* fc1_w = (const float*)d_in[8];
  const float* fc1_b = (const float*)d_in[9];
  const float* fc2_w = (const float*)d_in[10];
  const float* fc2_b = (const float*)d_in[11];

  char* ws = (char*)d_ws;
  float* xp = (float*)ws;                                        // [N,C] f32
  unsigned short* xn = (unsigned short*)(ws + 38535168);         // [N,C] bf16
  unsigned short* qkvb = (unsigned short*)(ws + 57802752);       // [N,1152] bf16
  unsigned short* abuf = (unsigned short*)(ws + 115605504);      // [N,C] bf16
  unsigned short* hbuf = qkvb;                                   // [N,1536] bf16 (reuse qkv+abuf)
  unsigned short* wq = (unsigned short*)(ws + 134873088);        // bricked weights
  unsigned short* wp = wq + 442368;
  unsigned short* wf1 = wp + 147456;
  unsigned short* wf2 = wf1 + 589824;

  repack_w<<<6912, 256, 0, stream>>>(qkv_w, proj_w, fc1_w, fc2_w, wq);
  tpose_ln<<<392, 256, 0, stream>>>(x, xp, xn, n1_g, n1_b);
  // grid: x = n-tiles (128 cols), y = m-tiles (128 rows)
  gemmK<0><<<dim3(9, 196), 256, 0, stream>>>(xn, wq, nullptr, nullptr, qkvb, C3_, C_);
  attn_kernel<<<1176, 256, 0, stream>>>(qkvb, xn, abuf);
  gemmK<1><<<dim3(3, 196), 256, 0, stream>>>(abuf, wp, proj_b, xp, xp, C_, C_);
  ln_rows<<<6272, 256, 0, stream>>>(xp, xn, n2_g, n2_b);
  gemmK<2><<<dim3(12, 196), 256, 0, stream>>>(xn, wf1, fc1_b, nullptr, hbuf, HID_, C_);
  gemmK<3><<<dim3(3, 196), 256, 0, stream>>>(hbuf, wf2, fc2_b, xp, d_out, C_, HID_);
}